// Round 15
// baseline (359.175 us; speedup 1.0000x reference)
//
#include <hip/hip_runtime.h>
#include <math.h>

#define B    256
#define NIN  1152
#define IND  8
#define NOUT 10
#define OUTD 16
#define M    160          // NOUT*OUTD
#define K    9216         // NIN*IND

typedef _Float16 h2    __attribute__((ext_vector_type(2)));
typedef _Float16 f16x4 __attribute__((ext_vector_type(4)));
typedef _Float16 f16x8 __attribute__((ext_vector_type(8)));
typedef float    f32x4 __attribute__((ext_vector_type(4)));
struct __align__(16) H8 { h2 h[4]; };   // 8 f16
struct __align__(8)  H4 { h2 h[2]; };   // 4 f16

// ================= fused prep: W -> {Wh, Wt}; u -> {u16, ut}; zero counters =========
// grid 1728 x 256: blocks [0,1152) = W-path (1 n each); [1152,1728) = u-path (64k x 64b tile).
__global__ __launch_bounds__(256) void k_prep(const float* __restrict__ W,
                                              const float* __restrict__ u,
                                              _Float16* __restrict__ Wh,
                                              _Float16* __restrict__ Wt,
                                              _Float16* __restrict__ u16,
                                              _Float16* __restrict__ ut,
                                              int* __restrict__ cnt) {
    __shared__ __align__(16) char smem[64 * 80 * 2];   // 10240 B (max of both paths)
    if (blockIdx.x == 0 && threadIdx.x < 48) cnt[threadIdx.x] = 0;

    if (blockIdx.x < NIN) {
        float* wl = (float*)smem;            // 5120 B
        const int n = blockIdx.x;
        const float* src = W + (size_t)n * IND * M;
        for (int t = threadIdx.x; t < IND * M / 4; t += 256)
            *(float4*)(wl + t * 4) = *(const float4*)(src + (size_t)t * 4);
        __syncthreads();
        _Float16* wh = Wh + (size_t)n * IND * M;
        for (int t = threadIdx.x; t < IND * M / 2; t += 256) {
            h2 p = {(_Float16)wl[2 * t], (_Float16)wl[2 * t + 1]};
            *(h2*)(wh + 2 * t) = p;
        }
        if (threadIdx.x < 160) {
            const int o = threadIdx.x >> 4, d = threadIdx.x & 15;
            f16x8 outv;
#pragma unroll
            for (int i = 0; i < IND; ++i) outv[i] = (_Float16)wl[i * M + o * OUTD + d];
            *(f16x8*)(Wt + (((size_t)n * NOUT + o) * OUTD + d) * IND) = outv;
        }
    } else {
        _Float16 (*lt)[80] = (_Float16(*)[80])smem;    // 64 x 80 f16, 10240 B
        const int idx = blockIdx.x - NIN;
        const int k0 = (idx % (K / 64)) * 64;          // 144 k-tiles
        const int b0 = (idx / (K / 64)) * 64;          // 4 b-tiles
#pragma unroll
        for (int p = 0; p < 4; ++p) {
            const int r = (threadIdx.x >> 4) + p * 16;   // b-local 0..63
            const int c = (threadIdx.x & 15) * 4;        // k-local
            const float4 f = *(const float4*)(u + (size_t)(b0 + r) * K + k0 + c);
            H4 pk;
            pk.h[0] = h2{(_Float16)f.x, (_Float16)f.y};
            pk.h[1] = h2{(_Float16)f.z, (_Float16)f.w};
            *(H4*)(u16 + (size_t)(b0 + r) * K + k0 + c) = pk;   // coalesced 8B
            lt[c + 0][r] = (_Float16)f.x;
            lt[c + 1][r] = (_Float16)f.y;
            lt[c + 2][r] = (_Float16)f.z;
            lt[c + 3][r] = (_Float16)f.w;
        }
        __syncthreads();
#pragma unroll
        for (int p = 0; p < 2; ++p) {
            const int kr = (threadIdx.x >> 3) + p * 32;  // k-local 0..63
            const int bc = (threadIdx.x & 7) * 8;        // b-local
            *(uint4*)(ut + (size_t)(k0 + kr) * B + b0 + bc) = *(const uint4*)&lt[kr][bc];
        }
    }
}

// ================= k_su + fused squash ==================
// MFMA core identical to verified round-14 form (4 waves, LDS pair-reduce).
// After spart write: threadfence -> atomicAdd(cnt[btile]) -> last of 48 blocks
// (acquire fence) reduces its btile's 16 b-rows over all splits and squashes.
#define NSPLIT 48
#define GPS    6      // n-groups (of 4 n) per split: 48*6*4 = 1152

template <int MODE, int OUT16>   // MODE: c uniform/cbuf; OUT16: vt f16 / out f32
__global__ __launch_bounds__(256, 8) void k_su(const _Float16* __restrict__ u16,
                                               const _Float16* __restrict__ Wt,
                                               const _Float16* __restrict__ cbuf,
                                               _Float16* __restrict__ spart,
                                               int* __restrict__ cnt,
                                               void* __restrict__ vdst) {
    __shared__ f32x4 red[2][5][64];         // 10240 B
    __shared__ int lastflag;
    const int lane  = threadIdx.x & 63;
    const int w     = threadIdx.x >> 6;     // 0..3
    const int wp    = w & 1;                // o-half
    const int gh    = w >> 1;               // g-half
    const int btile = blockIdx.x;           // 0..15
    const int split = blockIdx.y;           // 0..47
    const int bl    = lane & 15;            // A-row / b-local, B-col / d
    const int q     = lane >> 4;            // k-block = n offset within group
    const int b     = btile * 16 + bl;
    const int nbase = split * (GPS * 4);

    f32x4 acc[5];
#pragma unroll
    for (int j = 0; j < 5; ++j) acc[j] = f32x4{0.f, 0.f, 0.f, 0.f};

#pragma unroll
    for (int gg = 0; gg < 3; ++gg) {
        const int g = gh * 3 + gg;
        const int n = nbase + g * 4 + q;
        const f16x8 uf = *(const f16x8*)(u16 + ((size_t)b * NIN + n) * IND);
#pragma unroll
        for (int j = 0; j < 5; ++j) {
            const int o = wp * 5 + j;
            f16x8 a;
            if (MODE) {
                const _Float16 cv = cbuf[((size_t)o * NIN + n) * B + b];
#pragma unroll
                for (int i = 0; i < IND; ++i) a[i] = uf[i] * cv;
            } else {
                a = uf;
            }
            const f16x8 bf =
                *(const f16x8*)(Wt + (((size_t)n * NOUT + o) * OUTD + bl) * IND);
            acc[j] = __builtin_amdgcn_mfma_f32_16x16x32_f16(a, bf, acc[j], 0, 0, 0);
        }
    }

    if (gh == 1) {
#pragma unroll
        for (int j = 0; j < 5; ++j) red[wp][j][lane] = acc[j];
    }
    __syncthreads();
    if (gh == 0) {
        const float scale = MODE ? 1.0f : 0.1f;
        _Float16* sp = spart + (size_t)split * B * M + ((size_t)btile * 16) * M;
#pragma unroll
        for (int j = 0; j < 5; ++j) {
            const f32x4 other = red[wp][j][lane];
            const int o = wp * 5 + j;
#pragma unroll
            for (int r = 0; r < 4; ++r) {
                const int brow = q * 4 + r;
                sp[(size_t)brow * M + o * OUTD + bl] =
                    (_Float16)((acc[j][r] + other[r]) * scale);
            }
        }
    }

    // ---- fused squash: last arriving block of this btile reduces + squashes ----
    __threadfence();                        // release our spart stores (agent scope)
    __syncthreads();
    if (threadIdx.x == 0) lastflag = atomicAdd(cnt + btile, 1);
    __syncthreads();
    if (lastflag != NSPLIT - 1) return;
    __threadfence();                        // acquire: invalidate stale L2 lines

    const int b0s = btile * 16;
#pragma unroll
    for (int cc = 0; cc < 3; ++cc) {
        const int h = cc * 256 + threadIdx.x;     // H4 index within btile, 0..639
        if (h < 640) {
            const int bloc = h / 40, m4 = h % 40; // m4 = o*4 + dq
            const int o = m4 >> 2, dq = m4 & 3;
            const int bb = b0s + bloc;
            float s4[4] = {0.f, 0.f, 0.f, 0.f};
            const _Float16* base = spart + (size_t)bb * M + (size_t)m4 * 4;
#pragma unroll 8
            for (int ch = 0; ch < NSPLIT; ++ch) {
                const H4 p = *(const H4*)(base + (size_t)ch * B * M);
                s4[0] += (float)p.h[0][0]; s4[1] += (float)p.h[0][1];
                s4[2] += (float)p.h[1][0]; s4[3] += (float)p.h[1][1];
            }
            float ss = s4[0]*s4[0] + s4[1]*s4[1] + s4[2]*s4[2] + s4[3]*s4[3];
            ss += __shfl_xor(ss, 1);
            ss += __shfl_xor(ss, 2);        // 4-lane group = full 16 d's
            const float scl = sqrtf(ss) / (1.f + ss);
            if (OUT16) {
                H4 pk;
                pk.h[0] = h2{(_Float16)(s4[0]*scl), (_Float16)(s4[1]*scl)};
                pk.h[1] = h2{(_Float16)(s4[2]*scl), (_Float16)(s4[3]*scl)};
                *(H4*)((_Float16*)vdst + ((size_t)o * B + bb) * 16 + dq * 4) = pk;
            } else {
                float4 f = make_float4(s4[0]*scl, s4[1]*scl, s4[2]*scl, s4[3]*scl);
                *(float4*)((float*)vdst + (size_t)bb * M + o * OUTD + dq * 4) = f;
            }
        }
    }
}

// ================= k_a (MFMA v2, verified round-13): i in the REGISTER dim ==========
#define NPW  4     // n-pairs per block (one per wave)

template <int FIRST>
__global__ __launch_bounds__(256, 8) void k_a(const _Float16* __restrict__ ut,
                                              const _Float16* __restrict__ Wh,
                                              const _Float16* __restrict__ vt,
                                              _Float16* __restrict__ blog,
                                              _Float16* __restrict__ cbuf) {
    const int lane = threadIdx.x & 63;
    const int wv   = threadIdx.x >> 6;          // 0..3
    const int np   = blockIdx.x * NPW + wv;     // 0..575 n-pair
    const int col  = lane & 15;                 // b-local (B/C cols); A-row selector
    const int q    = lane >> 4;
    const int b0   = blockIdx.y * 16;
    const int b    = b0 + col;
    const int nl   = col >> 3, ii = col & 7;    // A-frag row -> (n_loc, i)
    const int nout = np * 2 + (q >> 1);         // n this lane owns post-reduction

    float uf[4];
    {
        const _Float16* up = ut + ((size_t)np * 16 + q * 4) * B + b;
#pragma unroll
        for (int r = 0; r < 4; ++r) uf[r] = (float)up[(size_t)r * B];
    }

    const _Float16* wa = Wh + (((size_t)np * 2 + nl) * IND + ii) * M + q * 4;
    const f32x4 zero = {0.f, 0.f, 0.f, 0.f};

    float areg[NOUT];
#pragma unroll
    for (int o = 0; o < NOUT; ++o) {
        const f16x4 af = *(const f16x4*)(wa + o * OUTD);                          // A
        const f16x4 bfr = *(const f16x4*)(vt + ((size_t)o * B + b) * 16 + q * 4); // B
        const f32x4 cp = __builtin_amdgcn_mfma_f32_16x16x16f16(af, bfr, zero, 0, 0, 0);
        float s = cp[0] * uf[0];
        s = fmaf(cp[1], uf[1], s);
        s = fmaf(cp[2], uf[2], s);
        s = fmaf(cp[3], uf[3], s);
        s += __shfl_xor(s, 16);     // q0+q1 -> n0 full i-sum; q2+q3 -> n1
        areg[o] = s;
    }

    float bl[NOUT];
    _Float16* bp = blog + ((size_t)nout * NOUT) * B + b;
    if (FIRST) {
#pragma unroll
        for (int o = 0; o < NOUT; ++o) {
            bl[o] = areg[o];
            if ((q & 1) == 0) bp[(size_t)o * B] = (_Float16)bl[o];
        }
    } else {
#pragma unroll
        for (int o = 0; o < NOUT; ++o) bl[o] = (float)bp[(size_t)o * B] + areg[o];
    }
    float mx = bl[0];
#pragma unroll
    for (int o = 1; o < NOUT; ++o) mx = fmaxf(mx, bl[o]);
    float sum = 0.f;
#pragma unroll
    for (int o = 0; o < NOUT; ++o) { bl[o] = __expf(bl[o] - mx); sum += bl[o]; }
    const float inv = 1.f / sum;
    if ((q & 1) == 0) {
#pragma unroll
        for (int o = 0; o < NOUT; ++o)
            cbuf[((size_t)o * NIN + nout) * B + b] = (_Float16)(bl[o] * inv);
    }
}

// ================= launch ==================
extern "C" void kernel_launch(void* const* d_in, const int* in_sizes, int n_in,
                              void* d_out, int out_size, void* d_ws, size_t ws_size,
                              hipStream_t stream) {
    const float* u = (const float*)d_in[0];   // [256,1152,8]
    const float* W = (const float*)d_in[1];   // [1152,8,160]
    float* out = (float*)d_out;               // [256,10,16] f32

    char* ws = (char*)d_ws;
    _Float16* spart0 = (_Float16*)(ws);                     //  3,932,160 B
    _Float16* spart1 = (_Float16*)(ws + 3932160);           //  3,932,160 B
    _Float16* spart2 = (_Float16*)(ws + 7864320);           //  3,932,160 B
    _Float16* blog   = (_Float16*)(ws + 11796480);          //  5,898,240 B
    _Float16* cbuf   = (_Float16*)(ws + 17694720);          //  5,898,240 B
    _Float16* vt     = (_Float16*)(ws + 23592960);          //     81,920 B
    _Float16* Wh     = (_Float16*)(ws + 23674880);          //  2,949,120 B
    _Float16* Wt     = (_Float16*)(ws + 26624000);          //  2,949,120 B
    _Float16* ut     = (_Float16*)(ws + 29573120);          //  4,718,592 B
    _Float16* u16    = (_Float16*)(ws + 34291712);          //  4,718,592 B
    int*      cnt    = (int*)(ws + 39010304);               //        192 B
    // total ~39.0 MB

    const dim3 gs(16, NSPLIT);                      // (16, 48) = 768 blocks
    const dim3 ga(NIN / 2 / NPW, B / 16);           // (144, 16)

    // fused one-time prep (also zeroes the 48 counters)
    k_prep<<<1728, 256, 0, stream>>>(W, u, Wh, Wt, u16, ut, cnt);

    // iter 0: s0 (+fused squash -> vt), a0
    k_su<0, 1><<<gs, 256, 0, stream>>>(u16, Wt, cbuf, spart0, cnt + 0, vt);
    k_a<1><<<ga, 256, 0, stream>>>(ut, Wh, vt, blog, cbuf);
    // iter 1: s1 (+squash -> vt), a1
    k_su<1, 1><<<gs, 256, 0, stream>>>(u16, Wt, cbuf, spart1, cnt + 16, vt);
    k_a<0><<<ga, 256, 0, stream>>>(ut, Wh, vt, blog, cbuf);
    // iter 2: s2 (+squash -> out f32)
    k_su<1, 0><<<gs, 256, 0, stream>>>(u16, Wt, cbuf, spart2, cnt + 32, out);
}

// Round 16
// 77.671 us; speedup vs baseline: 4.6243x; 4.6243x over previous
//
#include <hip/hip_runtime.h>
#include <math.h>

#define B    256
#define NIN  1152
#define IND  8
#define NOUT 10
#define OUTD 16
#define M    160          // NOUT*OUTD
#define K    9216         // NIN*IND

typedef _Float16 h2    __attribute__((ext_vector_type(2)));
typedef _Float16 f16x4 __attribute__((ext_vector_type(4)));
typedef _Float16 f16x8 __attribute__((ext_vector_type(8)));
typedef float    f32x4 __attribute__((ext_vector_type(4)));
struct __align__(16) H8 { h2 h[4]; };   // 8 f16
struct __align__(8)  H4 { h2 h[2]; };   // 4 f16

// ================= prep: W -> Wh (f16 same layout) + Wt [n][o][d][i] =================
__global__ __launch_bounds__(256) void k_prep_w(const float* __restrict__ W,
                                                _Float16* __restrict__ Wh,
                                                _Float16* __restrict__ Wt) {
    __shared__ float wl[IND * M];   // 5120 B
    const int n = blockIdx.x;
    const float* src = W + (size_t)n * IND * M;
    for (int t = threadIdx.x; t < IND * M / 4; t += 256)
        *(float4*)(wl + t * 4) = *(const float4*)(src + (size_t)t * 4);
    __syncthreads();
    // Wh: 640 h2 chunks
    _Float16* wh = Wh + (size_t)n * IND * M;
    for (int t = threadIdx.x; t < IND * M / 2; t += 256) {
        h2 p = {(_Float16)wl[2 * t], (_Float16)wl[2 * t + 1]};
        *(h2*)(wh + 2 * t) = p;
    }
    // Wt: [o][d][i]
    if (threadIdx.x < 160) {
        const int o = threadIdx.x >> 4, d = threadIdx.x & 15;
        f16x8 outv;
#pragma unroll
        for (int i = 0; i < IND; ++i) outv[i] = (_Float16)wl[i * M + o * OUTD + d];
        *(f16x8*)(Wt + (((size_t)n * NOUT + o) * OUTD + d) * IND) = outv;
    }
}

// ================= prep: u -> u16 (f16 same layout) + ut [k][b] transpose =================
__global__ __launch_bounds__(256) void k_prep_u(const float* __restrict__ u,
                                                _Float16* __restrict__ u16,
                                                _Float16* __restrict__ ut) {
    __shared__ _Float16 lt[64][80];   // pad 80 -> 160B row stride
    const int k0 = blockIdx.x * 64;   // 144
    const int b0 = blockIdx.y * 64;   // 4
#pragma unroll
    for (int p = 0; p < 4; ++p) {
        const int r = (threadIdx.x >> 4) + p * 16;   // b-local 0..63
        const int c = (threadIdx.x & 15) * 4;        // k-local
        const float4 f = *(const float4*)(u + (size_t)(b0 + r) * K + k0 + c);
        H4 pk;
        pk.h[0] = h2{(_Float16)f.x, (_Float16)f.y};
        pk.h[1] = h2{(_Float16)f.z, (_Float16)f.w};
        *(H4*)(u16 + (size_t)(b0 + r) * K + k0 + c) = pk;   // coalesced 8B
        lt[c + 0][r] = (_Float16)f.x;
        lt[c + 1][r] = (_Float16)f.y;
        lt[c + 2][r] = (_Float16)f.z;
        lt[c + 3][r] = (_Float16)f.w;
    }
    __syncthreads();
#pragma unroll
    for (int p = 0; p < 2; ++p) {
        const int kr = (threadIdx.x >> 3) + p * 32;  // k-local 0..63
        const int bc = (threadIdx.x & 7) * 8;        // b-local
        *(uint4*)(ut + (size_t)(k0 + kr) * B + b0 + bc) = *(const uint4*)&lt[kr][bc];
    }
}

// ================= k_su: MFMA 16x16x32 f16, 4-wave blocks, LDS pair-reduce ==========
// grid (16 btiles, 48 splits), 256 thr = 4 waves: wp = w&1 (o-half), gh = w>>1 (g-half).
// Each wave: 3 n-groups x 5 o MFMAs (verified round-11 fragment mapping).
// gh=1 waves dump acc to LDS; gh=0 waves add + write spart (halves spart traffic).
#define NSPLIT 48
#define GPS    6      // n-groups (of 4 n) per split: 48*6*4 = 1152

template <int MODE>   // 0: c = 0.1 uniform; 1: read cbuf (f16)
__global__ __launch_bounds__(256, 8) void k_su(const _Float16* __restrict__ u16,
                                               const _Float16* __restrict__ Wt,
                                               const _Float16* __restrict__ cbuf,
                                               _Float16* __restrict__ spart) {
    __shared__ f32x4 red[2][5][64];         // 10240 B
    const int lane  = threadIdx.x & 63;
    const int w     = threadIdx.x >> 6;     // 0..3
    const int wp    = w & 1;                // o-half
    const int gh    = w >> 1;               // g-half
    const int btile = blockIdx.x;           // 0..15
    const int split = blockIdx.y;           // 0..47
    const int bl    = lane & 15;            // A-row / b-local, B-col / d
    const int q     = lane >> 4;            // k-block = n offset within group
    const int b     = btile * 16 + bl;
    const int nbase = split * (GPS * 4);

    f32x4 acc[5];
#pragma unroll
    for (int j = 0; j < 5; ++j) acc[j] = f32x4{0.f, 0.f, 0.f, 0.f};

#pragma unroll
    for (int gg = 0; gg < 3; ++gg) {
        const int g = gh * 3 + gg;
        const int n = nbase + g * 4 + q;
        const f16x8 uf = *(const f16x8*)(u16 + ((size_t)b * NIN + n) * IND);
#pragma unroll
        for (int j = 0; j < 5; ++j) {
            const int o = wp * 5 + j;
            f16x8 a;
            if (MODE) {
                const _Float16 cv = cbuf[((size_t)o * NIN + n) * B + b];
#pragma unroll
                for (int i = 0; i < IND; ++i) a[i] = uf[i] * cv;
            } else {
                a = uf;
            }
            const f16x8 bf =
                *(const f16x8*)(Wt + (((size_t)n * NOUT + o) * OUTD + bl) * IND);
            acc[j] = __builtin_amdgcn_mfma_f32_16x16x32_f16(a, bf, acc[j], 0, 0, 0);
        }
    }

    if (gh == 1) {
#pragma unroll
        for (int j = 0; j < 5; ++j) red[wp][j][lane] = acc[j];
    }
    __syncthreads();
    if (gh == 0) {
        const float scale = MODE ? 1.0f : 0.1f;
        _Float16* sp = spart + (size_t)split * B * M + ((size_t)btile * 16) * M;
#pragma unroll
        for (int j = 0; j < 5; ++j) {
            const f32x4 other = red[wp][j][lane];
            const int o = wp * 5 + j;
#pragma unroll
            for (int r = 0; r < 4; ++r) {
                const int brow = q * 4 + r;
                sp[(size_t)brow * M + o * OUTD + bl] =
                    (_Float16)((acc[j][r] + other[r]) * scale);
            }
        }
    }
}

// ================= k_squash: reduce NSPLIT f16 partials + squash ==================
// grid 160 x 256. OUT16=1 -> vt[o][b][d16] f16 (k_a B-frag layout); OUT16=0 -> f32.
template <int OUT16>
__global__ __launch_bounds__(256) void k_squash(const _Float16* __restrict__ spart,
                                                void* __restrict__ dstv) {
    const int gid = blockIdx.x * 256 + threadIdx.x;   // 0..40959, = b*160+m
    float s = 0.f;
#pragma unroll 16
    for (int ch = 0; ch < NSPLIT; ++ch) s += (float)spart[(size_t)ch * B * M + gid];
    float ss = s * s;
    ss += __shfl_xor(ss, 1);
    ss += __shfl_xor(ss, 2);
    ss += __shfl_xor(ss, 4);
    ss += __shfl_xor(ss, 8);          // sum over the 16 d-lanes (16 | 64, aligned)
    const float v = s * sqrtf(ss) / (1.f + ss);
    if (OUT16) {
        const int b = gid / M, m = gid % M, o = m >> 4, d = m & 15;
        ((_Float16*)dstv)[((size_t)o * B + b) * 16 + d] = (_Float16)v;
    } else {
        ((float*)dstv)[gid] = v;
    }
}

// ================= k_a (MFMA v2, round-13 verified): i in the REGISTER dim ==========
#define NPW  4     // n-pairs per block (one per wave)

template <int FIRST>
__global__ __launch_bounds__(256, 8) void k_a(const _Float16* __restrict__ ut,
                                              const _Float16* __restrict__ Wh,
                                              const _Float16* __restrict__ vt,
                                              _Float16* __restrict__ blog,
                                              _Float16* __restrict__ cbuf) {
    const int lane = threadIdx.x & 63;
    const int wv   = threadIdx.x >> 6;          // 0..3
    const int np   = blockIdx.x * NPW + wv;     // 0..575 n-pair
    const int col  = lane & 15;                 // b-local (B/C cols); A-row selector
    const int q    = lane >> 4;
    const int b0   = blockIdx.y * 16;
    const int b    = b0 + col;
    const int nl   = col >> 3, ii = col & 7;    // A-frag row -> (n_loc, i)
    const int nout = np * 2 + (q >> 1);         // n this lane owns post-reduction

    float uf[4];
    {
        const _Float16* up = ut + ((size_t)np * 16 + q * 4) * B + b;
#pragma unroll
        for (int r = 0; r < 4; ++r) uf[r] = (float)up[(size_t)r * B];
    }

    const _Float16* wa = Wh + (((size_t)np * 2 + nl) * IND + ii) * M + q * 4;
    const f32x4 zero = {0.f, 0.f, 0.f, 0.f};

    float areg[NOUT];
#pragma unroll
    for (int o = 0; o < NOUT; ++o) {
        const f16x4 af = *(const f16x4*)(wa + o * OUTD);                          // A
        const f16x4 bfr = *(const f16x4*)(vt + ((size_t)o * B + b) * 16 + q * 4); // B
        const f32x4 cp = __builtin_amdgcn_mfma_f32_16x16x16f16(af, bfr, zero, 0, 0, 0);
        float s = cp[0] * uf[0];
        s = fmaf(cp[1], uf[1], s);
        s = fmaf(cp[2], uf[2], s);
        s = fmaf(cp[3], uf[3], s);
        s += __shfl_xor(s, 16);     // q0+q1 -> n0 full i-sum; q2+q3 -> n1
        areg[o] = s;
    }

    float bl[NOUT];
    _Float16* bp = blog + ((size_t)nout * NOUT) * B + b;
    if (FIRST) {
#pragma unroll
        for (int o = 0; o < NOUT; ++o) {
            bl[o] = areg[o];
            if ((q & 1) == 0) bp[(size_t)o * B] = (_Float16)bl[o];
        }
    } else {
#pragma unroll
        for (int o = 0; o < NOUT; ++o) bl[o] = (float)bp[(size_t)o * B] + areg[o];
    }
    float mx = bl[0];
#pragma unroll
    for (int o = 1; o < NOUT; ++o) mx = fmaxf(mx, bl[o]);
    float sum = 0.f;
#pragma unroll
    for (int o = 0; o < NOUT; ++o) { bl[o] = __expf(bl[o] - mx); sum += bl[o]; }
    const float inv = 1.f / sum;
    if ((q & 1) == 0) {
#pragma unroll
        for (int o = 0; o < NOUT; ++o)
            cbuf[((size_t)o * NIN + nout) * B + b] = (_Float16)(bl[o] * inv);
    }
}

// ================= launch ==================
extern "C" void kernel_launch(void* const* d_in, const int* in_sizes, int n_in,
                              void* d_out, int out_size, void* d_ws, size_t ws_size,
                              hipStream_t stream) {
    const float* u = (const float*)d_in[0];   // [256,1152,8]
    const float* W = (const float*)d_in[1];   // [1152,8,160]
    float* out = (float*)d_out;               // [256,10,16] f32

    char* ws = (char*)d_ws;
    _Float16* spart = (_Float16*)(ws);                      //  3,932,160 B
    _Float16* blog  = (_Float16*)(ws + 3932160);            //  5,898,240 B
    _Float16* cbuf  = (_Float16*)(ws + 9830400);            //  5,898,240 B
    _Float16* vt    = (_Float16*)(ws + 15728640);           //     81,920 B
    _Float16* Wh    = (_Float16*)(ws + 15810560);           //  2,949,120 B
    _Float16* Wt    = (_Float16*)(ws + 18759680);           //  2,949,120 B
    _Float16* ut    = (_Float16*)(ws + 21708800);           //  4,718,592 B
    _Float16* u16   = (_Float16*)(ws + 26427392);           //  4,718,592 B
    // total 31,145,984 B (~31.1 MB)

    const dim3 gs(16, NSPLIT);                      // (16, 48) = 768 blocks
    const dim3 ga(NIN / 2 / NPW, B / 16);           // (144, 16)

    // fused one-time preps
    k_prep_w<<<NIN, 256, 0, stream>>>(W, Wh, Wt);
    k_prep_u<<<dim3(K / 64, B / 64), 256, 0, stream>>>(u, u16, ut);

    // iter 0: uniform c = 0.1
    k_su<0><<<gs, 256, 0, stream>>>(u16, Wt, cbuf, spart);
    k_squash<1><<<160, 256, 0, stream>>>(spart, vt);
    // a0 -> blog=b1, c1
    k_a<1><<<ga, 256, 0, stream>>>(ut, Wh, vt, blog, cbuf);
    // s1 -> v1
    k_su<1><<<gs, 256, 0, stream>>>(u16, Wt, cbuf, spart);
    k_squash<1><<<160, 256, 0, stream>>>(spart, vt);
    // a1 -> b2 (in-register), c2
    k_a<0><<<ga, 256, 0, stream>>>(ut, Wh, vt, blog, cbuf);
    // s2 -> v2 = output
    k_su<1><<<gs, 256, 0, stream>>>(u16, Wt, cbuf, spart);
    k_squash<0><<<160, 256, 0, stream>>>(spart, out);
}

// Round 17
// 73.811 us; speedup vs baseline: 4.8662x; 1.0523x over previous
//
#include <hip/hip_runtime.h>
#include <math.h>

#define B    256
#define NIN  1152
#define IND  8
#define NOUT 10
#define OUTD 16
#define M    160          // NOUT*OUTD
#define K    9216         // NIN*IND

typedef _Float16 h2    __attribute__((ext_vector_type(2)));
typedef _Float16 f16x4 __attribute__((ext_vector_type(4)));
typedef _Float16 f16x8 __attribute__((ext_vector_type(8)));
typedef float    f32x4 __attribute__((ext_vector_type(4)));
struct __align__(16) H8 { h2 h[4]; };   // 8 f16
struct __align__(8)  H4 { h2 h[2]; };   // 4 f16

// ================= fused prep: W -> {Wh, Wt}; u -> {u16, ut} =================
// grid 1728 x 256: blocks [0,1152) = W-path (1 n each); [1152,1728) = u-path
// (64k x 64b tile). No cross-block communication (round-15's fence removed).
__global__ __launch_bounds__(256) void k_prep(const float* __restrict__ W,
                                              const float* __restrict__ u,
                                              _Float16* __restrict__ Wh,
                                              _Float16* __restrict__ Wt,
                                              _Float16* __restrict__ u16,
                                              _Float16* __restrict__ ut) {
    __shared__ __align__(16) char smem[64 * 80 * 2];   // 10240 B (max of both paths)

    if (blockIdx.x < NIN) {
        float* wl = (float*)smem;            // 5120 B
        const int n = blockIdx.x;
        const float* src = W + (size_t)n * IND * M;
        for (int t = threadIdx.x; t < IND * M / 4; t += 256)
            *(float4*)(wl + t * 4) = *(const float4*)(src + (size_t)t * 4);
        __syncthreads();
        _Float16* wh = Wh + (size_t)n * IND * M;
        for (int t = threadIdx.x; t < IND * M / 2; t += 256) {
            h2 p = {(_Float16)wl[2 * t], (_Float16)wl[2 * t + 1]};
            *(h2*)(wh + 2 * t) = p;
        }
        if (threadIdx.x < 160) {
            const int o = threadIdx.x >> 4, d = threadIdx.x & 15;
            f16x8 outv;
#pragma unroll
            for (int i = 0; i < IND; ++i) outv[i] = (_Float16)wl[i * M + o * OUTD + d];
            *(f16x8*)(Wt + (((size_t)n * NOUT + o) * OUTD + d) * IND) = outv;
        }
    } else {
        _Float16 (*lt)[80] = (_Float16(*)[80])smem;    // 64 x 80 f16, 10240 B
        const int idx = blockIdx.x - NIN;
        const int k0 = (idx % (K / 64)) * 64;          // 144 k-tiles
        const int b0 = (idx / (K / 64)) * 64;          // 4 b-tiles
#pragma unroll
        for (int p = 0; p < 4; ++p) {
            const int r = (threadIdx.x >> 4) + p * 16;   // b-local 0..63
            const int c = (threadIdx.x & 15) * 4;        // k-local
            const float4 f = *(const float4*)(u + (size_t)(b0 + r) * K + k0 + c);
            H4 pk;
            pk.h[0] = h2{(_Float16)f.x, (_Float16)f.y};
            pk.h[1] = h2{(_Float16)f.z, (_Float16)f.w};
            *(H4*)(u16 + (size_t)(b0 + r) * K + k0 + c) = pk;   // coalesced 8B
            lt[c + 0][r] = (_Float16)f.x;
            lt[c + 1][r] = (_Float16)f.y;
            lt[c + 2][r] = (_Float16)f.z;
            lt[c + 3][r] = (_Float16)f.w;
        }
        __syncthreads();
#pragma unroll
        for (int p = 0; p < 2; ++p) {
            const int kr = (threadIdx.x >> 3) + p * 32;  // k-local 0..63
            const int bc = (threadIdx.x & 7) * 8;        // b-local
            *(uint4*)(ut + (size_t)(k0 + kr) * B + b0 + bc) = *(const uint4*)&lt[kr][bc];
        }
    }
}

// ================= k_su: MFMA 16x16x32 f16, 4-wave blocks, LDS pair-reduce ==========
// grid (16 btiles, 48 splits), 256 thr = 4 waves: wp = w&1 (o-half), gh = w>>1 (g-half).
// Each wave: 3 n-groups x 5 o MFMAs (verified round-11 fragment mapping).
// gh=1 waves dump acc to LDS; gh=0 waves add + write spart (halves spart traffic).
#define NSPLIT 48
#define GPS    6      // n-groups (of 4 n) per split: 48*6*4 = 1152

template <int MODE>   // 0: c = 0.1 uniform; 1: read cbuf (f16)
__global__ __launch_bounds__(256, 8) void k_su(const _Float16* __restrict__ u16,
                                               const _Float16* __restrict__ Wt,
                                               const _Float16* __restrict__ cbuf,
                                               _Float16* __restrict__ spart) {
    __shared__ f32x4 red[2][5][64];         // 10240 B
    const int lane  = threadIdx.x & 63;
    const int w     = threadIdx.x >> 6;     // 0..3
    const int wp    = w & 1;                // o-half
    const int gh    = w >> 1;               // g-half
    const int btile = blockIdx.x;           // 0..15
    const int split = blockIdx.y;           // 0..47
    const int bl    = lane & 15;            // A-row / b-local, B-col / d
    const int q     = lane >> 4;            // k-block = n offset within group
    const int b     = btile * 16 + bl;
    const int nbase = split * (GPS * 4);

    f32x4 acc[5];
#pragma unroll
    for (int j = 0; j < 5; ++j) acc[j] = f32x4{0.f, 0.f, 0.f, 0.f};

#pragma unroll
    for (int gg = 0; gg < 3; ++gg) {
        const int g = gh * 3 + gg;
        const int n = nbase + g * 4 + q;
        const f16x8 uf = *(const f16x8*)(u16 + ((size_t)b * NIN + n) * IND);
#pragma unroll
        for (int j = 0; j < 5; ++j) {
            const int o = wp * 5 + j;
            f16x8 a;
            if (MODE) {
                const _Float16 cv = cbuf[((size_t)o * NIN + n) * B + b];
#pragma unroll
                for (int i = 0; i < IND; ++i) a[i] = uf[i] * cv;
            } else {
                a = uf;
            }
            const f16x8 bf =
                *(const f16x8*)(Wt + (((size_t)n * NOUT + o) * OUTD + bl) * IND);
            acc[j] = __builtin_amdgcn_mfma_f32_16x16x32_f16(a, bf, acc[j], 0, 0, 0);
        }
    }

    if (gh == 1) {
#pragma unroll
        for (int j = 0; j < 5; ++j) red[wp][j][lane] = acc[j];
    }
    __syncthreads();
    if (gh == 0) {
        const float scale = MODE ? 1.0f : 0.1f;
        _Float16* sp = spart + (size_t)split * B * M + ((size_t)btile * 16) * M;
#pragma unroll
        for (int j = 0; j < 5; ++j) {
            const f32x4 other = red[wp][j][lane];
            const int o = wp * 5 + j;
#pragma unroll
            for (int r = 0; r < 4; ++r) {
                const int brow = q * 4 + r;
                sp[(size_t)brow * M + o * OUTD + bl] =
                    (_Float16)((acc[j][r] + other[r]) * scale);
            }
        }
    }
}

// ================= k_squash: reduce NSPLIT f16 partials + squash ==================
// grid 160 x 256. OUT16=1 -> vt[o][b][d16] f16 (k_a B-frag layout); OUT16=0 -> f32.
template <int OUT16>
__global__ __launch_bounds__(256) void k_squash(const _Float16* __restrict__ spart,
                                                void* __restrict__ dstv) {
    const int gid = blockIdx.x * 256 + threadIdx.x;   // 0..40959, = b*160+m
    float s = 0.f;
#pragma unroll 16
    for (int ch = 0; ch < NSPLIT; ++ch) s += (float)spart[(size_t)ch * B * M + gid];
    float ss = s * s;
    ss += __shfl_xor(ss, 1);
    ss += __shfl_xor(ss, 2);
    ss += __shfl_xor(ss, 4);
    ss += __shfl_xor(ss, 8);          // sum over the 16 d-lanes (16 | 64, aligned)
    const float v = s * sqrtf(ss) / (1.f + ss);
    if (OUT16) {
        const int b = gid / M, m = gid % M, o = m >> 4, d = m & 15;
        ((_Float16*)dstv)[((size_t)o * B + b) * 16 + d] = (_Float16)v;
    } else {
        ((float*)dstv)[gid] = v;
    }
}

// ================= k_a (MFMA v2, round-13 verified): i in the REGISTER dim ==========
#define NPW  4     // n-pairs per block (one per wave)

template <int FIRST>
__global__ __launch_bounds__(256, 8) void k_a(const _Float16* __restrict__ ut,
                                              const _Float16* __restrict__ Wh,
                                              const _Float16* __restrict__ vt,
                                              _Float16* __restrict__ blog,
                                              _Float16* __restrict__ cbuf) {
    const int lane = threadIdx.x & 63;
    const int wv   = threadIdx.x >> 6;          // 0..3
    const int np   = blockIdx.x * NPW + wv;     // 0..575 n-pair
    const int col  = lane & 15;                 // b-local (B/C cols); A-row selector
    const int q    = lane >> 4;
    const int b0   = blockIdx.y * 16;
    const int b    = b0 + col;
    const int nl   = col >> 3, ii = col & 7;    // A-frag row -> (n_loc, i)
    const int nout = np * 2 + (q >> 1);         // n this lane owns post-reduction

    float uf[4];
    {
        const _Float16* up = ut + ((size_t)np * 16 + q * 4) * B + b;
#pragma unroll
        for (int r = 0; r < 4; ++r) uf[r] = (float)up[(size_t)r * B];
    }

    const _Float16* wa = Wh + (((size_t)np * 2 + nl) * IND + ii) * M + q * 4;
    const f32x4 zero = {0.f, 0.f, 0.f, 0.f};

    float areg[NOUT];
#pragma unroll
    for (int o = 0; o < NOUT; ++o) {
        const f16x4 af = *(const f16x4*)(wa + o * OUTD);                          // A
        const f16x4 bfr = *(const f16x4*)(vt + ((size_t)o * B + b) * 16 + q * 4); // B
        const f32x4 cp = __builtin_amdgcn_mfma_f32_16x16x16f16(af, bfr, zero, 0, 0, 0);
        float s = cp[0] * uf[0];
        s = fmaf(cp[1], uf[1], s);
        s = fmaf(cp[2], uf[2], s);
        s = fmaf(cp[3], uf[3], s);
        s += __shfl_xor(s, 16);     // q0+q1 -> n0 full i-sum; q2+q3 -> n1
        areg[o] = s;
    }

    float bl[NOUT];
    _Float16* bp = blog + ((size_t)nout * NOUT) * B + b;
    if (FIRST) {
#pragma unroll
        for (int o = 0; o < NOUT; ++o) {
            bl[o] = areg[o];
            if ((q & 1) == 0) bp[(size_t)o * B] = (_Float16)bl[o];
        }
    } else {
#pragma unroll
        for (int o = 0; o < NOUT; ++o) bl[o] = (float)bp[(size_t)o * B] + areg[o];
    }
    float mx = bl[0];
#pragma unroll
    for (int o = 1; o < NOUT; ++o) mx = fmaxf(mx, bl[o]);
    float sum = 0.f;
#pragma unroll
    for (int o = 0; o < NOUT; ++o) { bl[o] = __expf(bl[o] - mx); sum += bl[o]; }
    const float inv = 1.f / sum;
    if ((q & 1) == 0) {
#pragma unroll
        for (int o = 0; o < NOUT; ++o)
            cbuf[((size_t)o * NIN + nout) * B + b] = (_Float16)(bl[o] * inv);
    }
}

// ================= launch ==================
extern "C" void kernel_launch(void* const* d_in, const int* in_sizes, int n_in,
                              void* d_out, int out_size, void* d_ws, size_t ws_size,
                              hipStream_t stream) {
    const float* u = (const float*)d_in[0];   // [256,1152,8]
    const float* W = (const float*)d_in[1];   // [1152,8,160]
    float* out = (float*)d_out;               // [256,10,16] f32

    char* ws = (char*)d_ws;
    _Float16* spart = (_Float16*)(ws);                      //  3,932,160 B
    _Float16* blog  = (_Float16*)(ws + 3932160);            //  5,898,240 B
    _Float16* cbuf  = (_Float16*)(ws + 9830400);            //  5,898,240 B
    _Float16* vt    = (_Float16*)(ws + 15728640);           //     81,920 B
    _Float16* Wh    = (_Float16*)(ws + 15810560);           //  2,949,120 B
    _Float16* Wt    = (_Float16*)(ws + 18759680);           //  2,949,120 B
    _Float16* ut    = (_Float16*)(ws + 21708800);           //  4,718,592 B
    _Float16* u16   = (_Float16*)(ws + 26427392);           //  4,718,592 B
    // total 31,145,984 B (~31.1 MB)

    const dim3 gs(16, NSPLIT);                      // (16, 48) = 768 blocks
    const dim3 ga(NIN / 2 / NPW, B / 16);           // (144, 16)

    // fused one-time prep (W-path + u-path, no cross-block communication)
    k_prep<<<1728, 256, 0, stream>>>(W, u, Wh, Wt, u16, ut);

    // iter 0: uniform c = 0.1
    k_su<0><<<gs, 256, 0, stream>>>(u16, Wt, cbuf, spart);
    k_squash<1><<<160, 256, 0, stream>>>(spart, vt);
    // a0 -> blog=b1, c1
    k_a<1><<<ga, 256, 0, stream>>>(ut, Wh, vt, blog, cbuf);
    // s1 -> v1
    k_su<1><<<gs, 256, 0, stream>>>(u16, Wt, cbuf, spart);
    k_squash<1><<<160, 256, 0, stream>>>(spart, vt);
    // a1 -> b2 (in-register), c2
    k_a<0><<<ga, 256, 0, stream>>>(ut, Wh, vt, blog, cbuf);
    // s2 -> v2 = output
    k_su<1><<<gs, 256, 0, stream>>>(u16, Wt, cbuf, spart);
    k_squash<0><<<160, 256, 0, stream>>>(spart, out);
}

// Round 18
// 73.384 us; speedup vs baseline: 4.8944x; 1.0058x over previous
//
#include <hip/hip_runtime.h>
#include <math.h>

#define B    256
#define NIN  1152
#define IND  8
#define NOUT 10
#define OUTD 16
#define M    160          // NOUT*OUTD
#define K    9216         // NIN*IND

typedef _Float16 h2    __attribute__((ext_vector_type(2)));
typedef _Float16 f16x4 __attribute__((ext_vector_type(4)));
typedef _Float16 f16x8 __attribute__((ext_vector_type(8)));
typedef float    f32x4 __attribute__((ext_vector_type(4)));
struct __align__(16) H8 { h2 h[4]; };   // 8 f16
struct __align__(8)  H4 { h2 h[2]; };   // 4 f16

// ================= fused prep: W -> {Wh, Wt}; u -> {u2, ut} =================
// grid 1728 x 256: blocks [0,1152) = W-path (1 n each); [1152,1728) = u-path
// (64k x 64b tile). u2[n][b][i] f16 gives k_su 256B-contiguous fragment loads.
__global__ __launch_bounds__(256) void k_prep(const float* __restrict__ W,
                                              const float* __restrict__ u,
                                              _Float16* __restrict__ Wh,
                                              _Float16* __restrict__ Wt,
                                              _Float16* __restrict__ u2,
                                              _Float16* __restrict__ ut) {
    __shared__ __align__(16) char smem[64 * 80 * 2];   // 10240 B (max of both paths)

    if (blockIdx.x < NIN) {
        float* wl = (float*)smem;            // 5120 B
        const int n = blockIdx.x;
        const float* src = W + (size_t)n * IND * M;
        for (int t = threadIdx.x; t < IND * M / 4; t += 256)
            *(float4*)(wl + t * 4) = *(const float4*)(src + (size_t)t * 4);
        __syncthreads();
        _Float16* wh = Wh + (size_t)n * IND * M;
        for (int t = threadIdx.x; t < IND * M / 2; t += 256) {
            h2 p = {(_Float16)wl[2 * t], (_Float16)wl[2 * t + 1]};
            *(h2*)(wh + 2 * t) = p;
        }
        if (threadIdx.x < 160) {
            const int o = threadIdx.x >> 4, d = threadIdx.x & 15;
            f16x8 outv;
#pragma unroll
            for (int i = 0; i < IND; ++i) outv[i] = (_Float16)wl[i * M + o * OUTD + d];
            *(f16x8*)(Wt + (((size_t)n * NOUT + o) * OUTD + d) * IND) = outv;
        }
    } else {
        _Float16 (*lt)[80] = (_Float16(*)[80])smem;    // 64 x 80 f16, 10240 B
        const int idx = blockIdx.x - NIN;
        const int k0 = (idx % (K / 64)) * 64;          // 144 k-tiles
        const int b0 = (idx / (K / 64)) * 64;          // 4 b-tiles
#pragma unroll
        for (int p = 0; p < 4; ++p) {
            const int r = (threadIdx.x >> 4) + p * 16;   // b-local 0..63
            const int c = (threadIdx.x & 15) * 4;        // k-local
            const float4 f = *(const float4*)(u + (size_t)(b0 + r) * K + k0 + c);
            lt[c + 0][r] = (_Float16)f.x;
            lt[c + 1][r] = (_Float16)f.y;
            lt[c + 2][r] = (_Float16)f.z;
            lt[c + 3][r] = (_Float16)f.w;
        }
        __syncthreads();
        // ut [k][b]: 2x uint4 per thread, coalesced
#pragma unroll
        for (int p = 0; p < 2; ++p) {
            const int kr = (threadIdx.x >> 3) + p * 32;  // k-local 0..63
            const int bc = (threadIdx.x & 7) * 8;        // b-local
            *(uint4*)(ut + (size_t)(k0 + kr) * B + b0 + bc) = *(const uint4*)&lt[kr][bc];
        }
        // u2 [n][b][i]: 2x f16x8 per thread, consecutive threads -> consecutive b (16B) ✓
#pragma unroll
        for (int p = 0; p < 2; ++p) {
            const int idx2  = threadIdx.x + p * 256;     // 0..511
            const int n_loc = idx2 >> 6;                 // 0..7
            const int b_loc = idx2 & 63;                 // 0..63
            f16x8 v8;
#pragma unroll
            for (int i = 0; i < IND; ++i) v8[i] = lt[n_loc * 8 + i][b_loc];
            *(f16x8*)(u2 + ((size_t)((k0 >> 3) + n_loc) * B + (b0 + b_loc)) * IND) = v8;
        }
    }
}

// ================= k_su: MFMA 16x16x32 f16, 4-wave blocks, LDS pair-reduce ==========
// grid (16 btiles, 48 splits), 256 thr = 4 waves: wp = w&1 (o-half), gh = w>>1 (g-half).
// uf now reads u2[n][b][i] -> 16-lane group = 256B contiguous (was 18KB-stride gather).
#define NSPLIT 48
#define GPS    6      // n-groups (of 4 n) per split: 48*6*4 = 1152

template <int MODE>   // 0: c = 0.1 uniform; 1: read cbuf (f16)
__global__ __launch_bounds__(256, 8) void k_su(const _Float16* __restrict__ u2,
                                               const _Float16* __restrict__ Wt,
                                               const _Float16* __restrict__ cbuf,
                                               _Float16* __restrict__ spart) {
    __shared__ f32x4 red[2][5][64];         // 10240 B
    const int lane  = threadIdx.x & 63;
    const int w     = threadIdx.x >> 6;     // 0..3
    const int wp    = w & 1;                // o-half
    const int gh    = w >> 1;               // g-half
    const int btile = blockIdx.x;           // 0..15
    const int split = blockIdx.y;           // 0..47
    const int bl    = lane & 15;            // A-row / b-local, B-col / d
    const int q     = lane >> 4;            // k-block = n offset within group
    const int b     = btile * 16 + bl;
    const int nbase = split * (GPS * 4);

    f32x4 acc[5];
#pragma unroll
    for (int j = 0; j < 5; ++j) acc[j] = f32x4{0.f, 0.f, 0.f, 0.f};

#pragma unroll
    for (int gg = 0; gg < 3; ++gg) {
        const int g = gh * 3 + gg;
        const int n = nbase + g * 4 + q;
        const f16x8 uf = *(const f16x8*)(u2 + ((size_t)n * B + b) * IND);
#pragma unroll
        for (int j = 0; j < 5; ++j) {
            const int o = wp * 5 + j;
            f16x8 a;
            if (MODE) {
                const _Float16 cv = cbuf[((size_t)o * NIN + n) * B + b];
#pragma unroll
                for (int i = 0; i < IND; ++i) a[i] = uf[i] * cv;
            } else {
                a = uf;
            }
            const f16x8 bf =
                *(const f16x8*)(Wt + (((size_t)n * NOUT + o) * OUTD + bl) * IND);
            acc[j] = __builtin_amdgcn_mfma_f32_16x16x32_f16(a, bf, acc[j], 0, 0, 0);
        }
    }

    if (gh == 1) {
#pragma unroll
        for (int j = 0; j < 5; ++j) red[wp][j][lane] = acc[j];
    }
    __syncthreads();
    if (gh == 0) {
        const float scale = MODE ? 1.0f : 0.1f;
        _Float16* sp = spart + (size_t)split * B * M + ((size_t)btile * 16) * M;
#pragma unroll
        for (int j = 0; j < 5; ++j) {
            const f32x4 other = red[wp][j][lane];
            const int o = wp * 5 + j;
#pragma unroll
            for (int r = 0; r < 4; ++r) {
                const int brow = q * 4 + r;
                sp[(size_t)brow * M + o * OUTD + bl] =
                    (_Float16)((acc[j][r] + other[r]) * scale);
            }
        }
    }
}

// ================= k_squash: reduce NSPLIT f16 partials + squash ==================
// grid 160 x 256. OUT16=1 -> vt[o][b][d16] f16 (k_a B-frag layout); OUT16=0 -> f32.
template <int OUT16>
__global__ __launch_bounds__(256) void k_squash(const _Float16* __restrict__ spart,
                                                void* __restrict__ dstv) {
    const int gid = blockIdx.x * 256 + threadIdx.x;   // 0..40959, = b*160+m
    float s = 0.f;
#pragma unroll 16
    for (int ch = 0; ch < NSPLIT; ++ch) s += (float)spart[(size_t)ch * B * M + gid];
    float ss = s * s;
    ss += __shfl_xor(ss, 1);
    ss += __shfl_xor(ss, 2);
    ss += __shfl_xor(ss, 4);
    ss += __shfl_xor(ss, 8);          // sum over the 16 d-lanes (16 | 64, aligned)
    const float v = s * sqrtf(ss) / (1.f + ss);
    if (OUT16) {
        const int b = gid / M, m = gid % M, o = m >> 4, d = m & 15;
        ((_Float16*)dstv)[((size_t)o * B + b) * 16 + d] = (_Float16)v;
    } else {
        ((float*)dstv)[gid] = v;
    }
}

// ================= k_a (MFMA v2, round-13 verified): i in the REGISTER dim ==========
#define NPW  4     // n-pairs per block (one per wave)

template <int FIRST>
__global__ __launch_bounds__(256, 8) void k_a(const _Float16* __restrict__ ut,
                                              const _Float16* __restrict__ Wh,
                                              const _Float16* __restrict__ vt,
                                              _Float16* __restrict__ blog,
                                              _Float16* __restrict__ cbuf) {
    const int lane = threadIdx.x & 63;
    const int wv   = threadIdx.x >> 6;          // 0..3
    const int np   = blockIdx.x * NPW + wv;     // 0..575 n-pair
    const int col  = lane & 15;                 // b-local (B/C cols); A-row selector
    const int q    = lane >> 4;
    const int b0   = blockIdx.y * 16;
    const int b    = b0 + col;
    const int nl   = col >> 3, ii = col & 7;    // A-frag row -> (n_loc, i)
    const int nout = np * 2 + (q >> 1);         // n this lane owns post-reduction

    float uf[4];
    {
        const _Float16* up = ut + ((size_t)np * 16 + q * 4) * B + b;
#pragma unroll
        for (int r = 0; r < 4; ++r) uf[r] = (float)up[(size_t)r * B];
    }

    const _Float16* wa = Wh + (((size_t)np * 2 + nl) * IND + ii) * M + q * 4;
    const f32x4 zero = {0.f, 0.f, 0.f, 0.f};

    float areg[NOUT];
#pragma unroll
    for (int o = 0; o < NOUT; ++o) {
        const f16x4 af = *(const f16x4*)(wa + o * OUTD);                          // A
        const f16x4 bfr = *(const f16x4*)(vt + ((size_t)o * B + b) * 16 + q * 4); // B
        const f32x4 cp = __builtin_amdgcn_mfma_f32_16x16x16f16(af, bfr, zero, 0, 0, 0);
        float s = cp[0] * uf[0];
        s = fmaf(cp[1], uf[1], s);
        s = fmaf(cp[2], uf[2], s);
        s = fmaf(cp[3], uf[3], s);
        s += __shfl_xor(s, 16);     // q0+q1 -> n0 full i-sum; q2+q3 -> n1
        areg[o] = s;
    }

    float bl[NOUT];
    _Float16* bp = blog + ((size_t)nout * NOUT) * B + b;
    if (FIRST) {
#pragma unroll
        for (int o = 0; o < NOUT; ++o) {
            bl[o] = areg[o];
            if ((q & 1) == 0) bp[(size_t)o * B] = (_Float16)bl[o];
        }
    } else {
#pragma unroll
        for (int o = 0; o < NOUT; ++o) bl[o] = (float)bp[(size_t)o * B] + areg[o];
    }
    float mx = bl[0];
#pragma unroll
    for (int o = 1; o < NOUT; ++o) mx = fmaxf(mx, bl[o]);
    float sum = 0.f;
#pragma unroll
    for (int o = 0; o < NOUT; ++o) { bl[o] = __expf(bl[o] - mx); sum += bl[o]; }
    const float inv = 1.f / sum;
    if ((q & 1) == 0) {
#pragma unroll
        for (int o = 0; o < NOUT; ++o)
            cbuf[((size_t)o * NIN + nout) * B + b] = (_Float16)(bl[o] * inv);
    }
}

// ================= launch ==================
extern "C" void kernel_launch(void* const* d_in, const int* in_sizes, int n_in,
                              void* d_out, int out_size, void* d_ws, size_t ws_size,
                              hipStream_t stream) {
    const float* u = (const float*)d_in[0];   // [256,1152,8]
    const float* W = (const float*)d_in[1];   // [1152,8,160]
    float* out = (float*)d_out;               // [256,10,16] f32

    char* ws = (char*)d_ws;
    _Float16* spart = (_Float16*)(ws);                      //  3,932,160 B
    _Float16* blog  = (_Float16*)(ws + 3932160);            //  5,898,240 B
    _Float16* cbuf  = (_Float16*)(ws + 9830400);            //  5,898,240 B
    _Float16* vt    = (_Float16*)(ws + 15728640);           //     81,920 B
    _Float16* Wh    = (_Float16*)(ws + 15810560);           //  2,949,120 B
    _Float16* Wt    = (_Float16*)(ws + 18759680);           //  2,949,120 B
    _Float16* ut    = (_Float16*)(ws + 21708800);           //  4,718,592 B
    _Float16* u2    = (_Float16*)(ws + 26427392);           //  4,718,592 B
    // total 31,145,984 B (~31.1 MB)

    const dim3 gs(16, NSPLIT);                      // (16, 48) = 768 blocks
    const dim3 ga(NIN / 2 / NPW, B / 16);           // (144, 16)

    // fused one-time prep (W-path + u-path)
    k_prep<<<1728, 256, 0, stream>>>(W, u, Wh, Wt, u2, ut);

    // iter 0: uniform c = 0.1
    k_su<0><<<gs, 256, 0, stream>>>(u2, Wt, cbuf, spart);
    k_squash<1><<<160, 256, 0, stream>>>(spart, vt);
    // a0 -> blog=b1, c1
    k_a<1><<<ga, 256, 0, stream>>>(ut, Wh, vt, blog, cbuf);
    // s1 -> v1
    k_su<1><<<gs, 256, 0, stream>>>(u2, Wt, cbuf, spart);
    k_squash<1><<<160, 256, 0, stream>>>(spart, vt);
    // a1 -> b2 (in-register), c2
    k_a<0><<<ga, 256, 0, stream>>>(ut, Wh, vt, blog, cbuf);
    // s2 -> v2 = output
    k_su<1><<<gs, 256, 0, stream>>>(u2, Wt, cbuf, spart);
    k_squash<0><<<160, 256, 0, stream>>>(spart, out);
}